// Round 5
// baseline (309.289 us; speedup 1.0000x reference)
//
#include <hip/hip_runtime.h>
#include <math.h>

#define NROWS 65536
#define DIM   512
#define NCLS  64
#define CCAP  1280   // per-class bucket capacity (mean 1024, sd ~32 -> 8 sigma)

typedef __attribute__((ext_vector_type(4))) float f32x4;
typedef __attribute__((ext_vector_type(8))) short s16x8;

// ws layout (4-byte words):
//   [0..32768)      protoSum[64][512] f32   (zeroed)
//   [32768..32832)  cursors[64] i32         (zeroed; == counts after scatter)
//   32832 lossAcc   32833 accAcc   32834 doneCnt   (zeroed)
//   [32836..32900)  p2[64] f32
//   [32912..114832) perm[64*1280] i32 ; pB bf16[64*512] overlays its start
#define WS_PROTOSUM 0
#define WS_CURSORS  32768
#define WS_LOSS     32832
#define WS_ACC      32833
#define WS_DONE     32834
#define WS_P2       32836
#define WS_PERM     32912
#define WS_PB       32912
#define MEMSET_WORDS 32835

static __device__ __forceinline__ unsigned short f2bf(float f) {
    unsigned int u = __float_as_uint(f);
    u += 0x7FFF + ((u >> 16) & 1);   // RNE
    return (unsigned short)(u >> 16);
}
static __device__ __forceinline__ float bf2f(unsigned short h) {
    return __uint_as_float(((unsigned int)h) << 16);
}

// ---------------- scatter rows into fixed-stride class buckets ------------
__global__ __launch_bounds__(256) void k_scatter(const int* __restrict__ labels,
                                                 int* __restrict__ cursors,
                                                 int* __restrict__ perm) {
    __shared__ int lh[NCLS], lb[NCLS];
    int t = threadIdx.x;
    if (t < NCLS) lh[t] = 0;
    __syncthreads();
    int i = blockIdx.x * 256 + t;
    int lab = labels[i];
    int rank = atomicAdd(&lh[lab], 1);
    __syncthreads();
    if (t < NCLS) lb[t] = atomicAdd(&cursors[t], lh[t]);
    __syncthreads();
    int pos = lb[lab] + rank;
    if (pos < CCAP) perm[lab * CCAP + pos] = i;
}

// ---------------- per-class partial sums, float4 register accumulation ----
// grid = 64 classes x 4 dim-chunks x 8 row-splits = 2048 blocks
// block = 256 thr = 8 row-groups (g) x 32 dim-lanes (float4 = 128 dims)
__global__ __launch_bounds__(256) void k_psum(const float* __restrict__ emb,
                                              const int* __restrict__ cursors,
                                              const int* __restrict__ perm,
                                              float* __restrict__ protoSum) {
    __shared__ int permS[CCAP];
    __shared__ float4 red[256];
    int t   = threadIdx.x;
    int c   = blockIdx.x >> 5;
    int sub = blockIdx.x & 31;
    int dc  = sub & 3;        // dim chunk (128 dims)
    int rs  = sub >> 2;       // row split 0..7
    int tl  = t & 31;
    int g   = t >> 5;         // 0..7

    int cnt = cursors[c];
    int n = (cnt < CCAP) ? cnt : CCAP;
    for (int i = t; i < n; i += 256) permS[i] = perm[c * CCAP + i];
    __syncthreads();

    const float4* eb = (const float4*)emb + dc * 32 + tl;
    float4 acc = make_float4(0.f, 0.f, 0.f, 0.f);
#pragma unroll 4
    for (int i = rs * 8 + g; i < n; i += 64) {
        int r = permS[i];                       // LDS broadcast
        float4 v = eb[(size_t)r * 128];         // 512B contiguous per row-grp
        acc.x += v.x; acc.y += v.y; acc.z += v.z; acc.w += v.w;
    }
    red[t] = acc;
    __syncthreads();
    if (t < 32) {
        float4 s = red[t];
#pragma unroll
        for (int gg = 1; gg < 8; ++gg) {
            float4 v = red[gg * 32 + t];
            s.x += v.x; s.y += v.y; s.z += v.z; s.w += v.w;
        }
        float* dst = &protoSum[(size_t)c * DIM + dc * 128 + t * 4];
        atomicAdd(dst + 0, s.x);
        atomicAdd(dst + 1, s.y);
        atomicAdd(dst + 2, s.z);
        atomicAdd(dst + 3, s.w);
    }
}

// ---------------- finalize prototypes: mean -> bf16 B[n][k], p2 -----------
__global__ __launch_bounds__(512) void k_protofin(const float* __restrict__ protoSum,
                                                  const int* __restrict__ cursors,
                                                  unsigned short* __restrict__ pB,
                                                  float* __restrict__ p2) {
    int c = blockIdx.x, d = threadIdx.x;
    float mean = protoSum[(size_t)c * DIM + d] / (float)cursors[c];
    unsigned short mb = f2bf(mean);
    pB[(size_t)c * DIM + d] = mb;       // [n][k] for MFMA B-frags
    float mf = bf2f(mb);
    float sq = mf * mf;
#pragma unroll
    for (int o = 32; o > 0; o >>= 1) sq += __shfl_down(sq, o, 64);
    __shared__ float red[8];
    if ((d & 63) == 0) red[d >> 6] = sq;
    __syncthreads();
    if (d == 0) {
        float ss = 0.f;
#pragma unroll
        for (int w = 0; w < 8; ++w) ss += red[w];
        p2[c] = ss;
    }
}

// ---------------- main: barrier-free MFMA K-loop + softmax + reduce -------
// grid = 1024 x 256; 64 rows/block, wave wv owns rows wv*16..+15.
// A-frags loaded per-lane straight from global (row-contiguous 128B/row/kc);
// no LDS staging, no barriers in the K-loop.
#define LROWS 64
#define LGRID (NROWS / LROWS)
__global__ __launch_bounds__(256) void k_logits(const float* __restrict__ emb,
                                                const int* __restrict__ labels,
                                                const unsigned short* __restrict__ pB,
                                                const float* __restrict__ p2,
                                                float* __restrict__ lossAcc,
                                                float* __restrict__ accAcc,
                                                unsigned int* __restrict__ doneCnt,
                                                float* __restrict__ out) {
    __shared__ float e2s[LROWS];
    __shared__ float rb[8];

    int t    = threadIdx.x;
    int lane = t & 63;
    int wv   = t >> 6;
    int quad = lane >> 4;
    int l15  = lane & 15;
    int rbase = blockIdx.x * LROWS;

    f32x4 acc[4];
#pragma unroll
    for (int nt = 0; nt < 4; ++nt) acc[nt] = (f32x4){0.f, 0.f, 0.f, 0.f};
    float e2a = 0.f;

    // this lane's row: rbase + wv*16 + l15; k-octet = kc*32 + quad*8
    const float4* arow = (const float4*)(emb + (size_t)(rbase + wv * 16 + l15) * DIM)
                         + quad * 2;
    const unsigned short* bbase = pB + (size_t)l15 * DIM + quad * 8;

    for (int kc = 0; kc < 16; ++kc) {
        float4 a0 = arow[kc * 8 + 0];
        float4 a1 = arow[kc * 8 + 1];
        s16x8 bf[4];
#pragma unroll
        for (int nt = 0; nt < 4; ++nt)
            bf[nt] = *(const s16x8*)(bbase + (size_t)nt * 16 * DIM + kc * 32);
        e2a += a0.x * a0.x + a0.y * a0.y + a0.z * a0.z + a0.w * a0.w;
        e2a += a1.x * a1.x + a1.y * a1.y + a1.z * a1.z + a1.w * a1.w;
        s16x8 af;
        af[0] = (short)f2bf(a0.x); af[1] = (short)f2bf(a0.y);
        af[2] = (short)f2bf(a0.z); af[3] = (short)f2bf(a0.w);
        af[4] = (short)f2bf(a1.x); af[5] = (short)f2bf(a1.y);
        af[6] = (short)f2bf(a1.z); af[7] = (short)f2bf(a1.w);
#pragma unroll
        for (int nt = 0; nt < 4; ++nt)
            acc[nt] = __builtin_amdgcn_mfma_f32_16x16x32_bf16(af, bf[nt], acc[nt], 0, 0, 0);
    }

    // e2: combine the 4 quads of each row (lanes l15, +16, +32, +48)
    e2a += __shfl_xor(e2a, 16, 64);
    e2a += __shfl_xor(e2a, 32, 64);
    if (lane < 16) e2s[wv * 16 + lane] = e2a;
    __syncthreads();

    // epilogue: C/D layout col = nt*16 + l15, row = quad*4 + reg
    float nlls = 0.f, corr = 0.f;
#pragma unroll
    for (int reg = 0; reg < 4; ++reg) {
        int rloc = wv * 16 + quad * 4 + reg;
        float e2v = e2s[rloc];
        float lg[4];
#pragma unroll
        for (int nt = 0; nt < 4; ++nt) {
            float d2 = e2v + p2[nt * 16 + l15] - 2.f * acc[nt][reg];
            d2 = fmaxf(d2, 1e-12f);
            lg[nt] = -sqrtf(d2);
        }
        float mv = lg[0]; int mc = l15;
#pragma unroll
        for (int nt = 1; nt < 4; ++nt) {
            int cix = nt * 16 + l15;
            if (lg[nt] > mv) { mv = lg[nt]; mc = cix; }
        }
#pragma unroll
        for (int o = 1; o < 16; o <<= 1) {
            float mo = __shfl_xor(mv, o, 64);
            int   co = __shfl_xor(mc, o, 64);
            if (mo > mv || (mo == mv && co < mc)) { mv = mo; mc = co; }
        }
        int lab = labels[rbase + rloc];
        float se = 0.f, ll = 0.f;
#pragma unroll
        for (int nt = 0; nt < 4; ++nt) se += __expf(lg[nt] - mv);
        if ((lab & 15) == l15) ll = lg[lab >> 4];
#pragma unroll
        for (int o = 1; o < 16; o <<= 1) {
            se += __shfl_xor(se, o, 64);
            ll += __shfl_xor(ll, o, 64);
        }
        if (l15 == 0) {
            nlls += __logf(se) + mv - ll;
            corr += (mc == lab) ? 1.f : 0.f;
        }
    }
#pragma unroll
    for (int o = 1; o < 64; o <<= 1) {
        nlls += __shfl_xor(nlls, o, 64);
        corr += __shfl_xor(corr, o, 64);
    }
    if (lane == 0) { rb[wv] = nlls; rb[4 + wv] = corr; }
    __syncthreads();
    if (t == 0) {
        atomicAdd(lossAcc, rb[0] + rb[1] + rb[2] + rb[3]);
        atomicAdd(accAcc, rb[4] + rb[5] + rb[6] + rb[7]);
        __threadfence();
        unsigned int tk = atomicAdd(doneCnt, 1u);
        if (tk == LGRID - 1) {   // last block: all atomics visible
            float ls = atomicAdd(lossAcc, 0.f);   // device-scope read
            float as_ = atomicAdd(accAcc, 0.f);
            out[0] = ls * (1.f / NROWS);
            out[1] = as_ * (1.f / NROWS);
        }
    }
}

extern "C" void kernel_launch(void* const* d_in, const int* in_sizes, int n_in,
                              void* d_out, int out_size, void* d_ws, size_t ws_size,
                              hipStream_t stream) {
    const float* emb    = (const float*)d_in[0];
    const int*   labels = (const int*)d_in[1];
    float* out = (float*)d_out;

    float* wsf = (float*)d_ws;
    int*   wsi = (int*)d_ws;
    float*          protoSum = wsf + WS_PROTOSUM;
    int*            cursors  = wsi + WS_CURSORS;
    float*          lossAcc  = wsf + WS_LOSS;
    float*          accAcc   = wsf + WS_ACC;
    unsigned int*   doneCnt  = (unsigned int*)(wsi + WS_DONE);
    float*          p2       = wsf + WS_P2;
    int*            perm     = wsi + WS_PERM;
    unsigned short* pB       = (unsigned short*)(wsf + WS_PB);  // overlays perm

    hipMemsetAsync(d_ws, 0, MEMSET_WORDS * sizeof(int), stream);

    k_scatter<<<NROWS / 256, 256, 0, stream>>>(labels, cursors, perm);
    k_psum<<<NCLS * 32, 256, 0, stream>>>(emb, cursors, perm, protoSum);
    k_protofin<<<NCLS, 512, 0, stream>>>(protoSum, cursors, pB, p2);
    k_logits<<<LGRID, 256, 0, stream>>>(emb, labels, pB, p2,
                                        lossAcc, accAcc, doneCnt, out);
}

// Round 6
// 270.838 us; speedup vs baseline: 1.1420x; 1.1420x over previous
//
#include <hip/hip_runtime.h>
#include <math.h>

#define NROWS 65536
#define DIM   512
#define NCLS  64
#define CCAP  1280   // per-class bucket capacity (mean 1024, sd ~32 -> 8 sigma)

typedef __attribute__((ext_vector_type(4))) float f32x4;
typedef __attribute__((ext_vector_type(8))) short s16x8;

// ws layout (4-byte words):
//   [0..32768)      protoSum[64][512] f32   (zeroed)
//   [32768..32832)  cursors[64] i32         (zeroed; == counts after scatter)
//   32832 lossAcc   32833 accAcc   32834 doneCnt   (zeroed)
//   [32836..32900)  p2[64] f32
//   [32912..114832) perm[64*1280] i32
//   [114944..131328) pBf bf16[64*512] in MFMA B-fragment order
#define WS_PROTOSUM 0
#define WS_CURSORS  32768
#define WS_LOSS     32832
#define WS_ACC      32833
#define WS_DONE     32834
#define WS_P2       32836
#define WS_PERM     32912
#define WS_PBF      114944           // byte 459776, 16B aligned
#define MEMSET_WORDS 32835

static __device__ __forceinline__ unsigned short f2bf(float f) {
    unsigned int u = __float_as_uint(f);
    u += 0x7FFF + ((u >> 16) & 1);   // RNE
    return (unsigned short)(u >> 16);
}
static __device__ __forceinline__ float bf2f(unsigned short h) {
    return __uint_as_float(((unsigned int)h) << 16);
}

// ---------------- scatter rows into fixed-stride class buckets ------------
__global__ __launch_bounds__(256) void k_scatter(const int* __restrict__ labels,
                                                 int* __restrict__ cursors,
                                                 int* __restrict__ perm) {
    __shared__ int lh[NCLS], lb[NCLS];
    int t = threadIdx.x;
    if (t < NCLS) lh[t] = 0;
    __syncthreads();
    int i = blockIdx.x * 256 + t;
    int lab = labels[i];
    int rank = atomicAdd(&lh[lab], 1);
    __syncthreads();
    if (t < NCLS) lb[t] = atomicAdd(&cursors[t], lh[t]);
    __syncthreads();
    int pos = lb[lab] + rank;
    if (pos < CCAP) perm[lab * CCAP + pos] = i;
}

// ---------------- per-class partial sums, float4 register accumulation ----
// grid = 64 classes x 4 dim-chunks x 8 row-splits = 2048 blocks
__global__ __launch_bounds__(256) void k_psum(const float* __restrict__ emb,
                                              const int* __restrict__ cursors,
                                              const int* __restrict__ perm,
                                              float* __restrict__ protoSum) {
    __shared__ int permS[CCAP];
    __shared__ float4 red[256];
    int t   = threadIdx.x;
    int c   = blockIdx.x >> 5;
    int sub = blockIdx.x & 31;
    int dc  = sub & 3;        // dim chunk (128 dims)
    int rs  = sub >> 2;       // row split 0..7
    int tl  = t & 31;
    int g   = t >> 5;         // 0..7

    int cnt = cursors[c];
    int n = (cnt < CCAP) ? cnt : CCAP;
    for (int i = t; i < n; i += 256) permS[i] = perm[c * CCAP + i];
    __syncthreads();

    const float4* eb = (const float4*)emb + dc * 32 + tl;
    float4 acc = make_float4(0.f, 0.f, 0.f, 0.f);
#pragma unroll 4
    for (int i = rs * 8 + g; i < n; i += 64) {
        int r = permS[i];                       // LDS broadcast
        float4 v = eb[(size_t)r * 128];         // 512B contiguous per row-grp
        acc.x += v.x; acc.y += v.y; acc.z += v.z; acc.w += v.w;
    }
    red[t] = acc;
    __syncthreads();
    if (t < 32) {
        float4 s = red[t];
#pragma unroll
        for (int gg = 1; gg < 8; ++gg) {
            float4 v = red[gg * 32 + t];
            s.x += v.x; s.y += v.y; s.z += v.z; s.w += v.w;
        }
        float* dst = &protoSum[(size_t)c * DIM + dc * 128 + t * 4];
        atomicAdd(dst + 0, s.x);
        atomicAdd(dst + 1, s.y);
        atomicAdd(dst + 2, s.z);
        atomicAdd(dst + 3, s.w);
    }
}

// ---- finalize prototypes: mean -> bf16 B in MFMA fragment order, p2 ------
// pBf layout: shorts idx = (((kc*4+quad)*4+nt)*16 + l15)*8 + j
// where k = kc*32+quad*8+j, n = nt*16+l15 -> wave B-frag loads are
// lane-contiguous (4 x 256B segments per instruction).
__global__ __launch_bounds__(512) void k_protofin(const float* __restrict__ protoSum,
                                                  const int* __restrict__ cursors,
                                                  unsigned short* __restrict__ pBf,
                                                  float* __restrict__ p2) {
    int c = blockIdx.x, d = threadIdx.x;
    float mean = protoSum[(size_t)c * DIM + d] / (float)cursors[c];
    unsigned short mb = f2bf(mean);
    int kc = d >> 5, quad = (d >> 3) & 3, j = d & 7;
    int nt = c >> 4, l15 = c & 15;
    pBf[(size_t)(((kc * 4 + quad) * 4 + nt) * 16 + l15) * 8 + j] = mb;
    float mf = bf2f(mb);
    float sq = mf * mf;
#pragma unroll
    for (int o = 32; o > 0; o >>= 1) sq += __shfl_down(sq, o, 64);
    __shared__ float red[8];
    if ((d & 63) == 0) red[d >> 6] = sq;
    __syncthreads();
    if (d == 0) {
        float ss = 0.f;
#pragma unroll
        for (int w = 0; w < 8; ++w) ss += red[w];
        p2[c] = ss;
    }
}

// ---------------- main: MFMA + dbuf LDS + raw-barrier K-loop --------------
// grid = 1024 x 256; 64 rows/block; wave wv owns rows wv*16..+15.
// Coalesced global->reg->LDS staging; A/B prefetch stays in flight across
// the raw s_barrier (lgkmcnt-only drain - NOT __syncthreads' vmcnt(0)).
#define LROWS 64
#define LGRID (NROWS / LROWS)
__global__ __launch_bounds__(256) void k_logits(const float* __restrict__ emb,
                                                const int* __restrict__ labels,
                                                const unsigned short* __restrict__ pBf,
                                                const float* __restrict__ p2,
                                                float* __restrict__ lossAcc,
                                                float* __restrict__ accAcc,
                                                unsigned int* __restrict__ doneCnt,
                                                float* __restrict__ out) {
    __shared__ __align__(16) unsigned short Asm[2][LROWS * 36]; // stride 36
    __shared__ float e2s[LROWS];
    __shared__ float rb[8];

    int t    = threadIdx.x;
    int lane = t & 63;
    int wv   = t >> 6;
    int quad = lane >> 4;
    int l15  = lane & 15;
    int rbase = blockIdx.x * LROWS;

    f32x4 acc[4];
#pragma unroll
    for (int nt = 0; nt < 4; ++nt) acc[nt] = (f32x4){0.f, 0.f, 0.f, 0.f};
    float e2a0 = 0.f, e2a1 = 0.f;

    const float4* emb4 = (const float4*)(emb + (size_t)rbase * DIM);
    int row0 = t >> 3, j0 = t & 7;   // rows 0..31
    int row1 = 32 + row0;            // rows 32..63

    // preload kc = 0 (A rows + B frags)
    float4 g0 = emb4[(size_t)row0 * 128 + j0];
    float4 g1 = emb4[(size_t)row1 * 128 + j0];
    s16x8 bf[4];
#pragma unroll
    for (int nt = 0; nt < 4; ++nt)
        bf[nt] = *(const s16x8*)(pBf + (size_t)((quad * 4 + nt) * 16 + l15) * 8);

#pragma unroll 4
    for (int kc = 0; kc < 16; ++kc) {
        int buf = kc & 1;
        // convert + e2 + stage to LDS (coalesced pattern, verified 0 conflicts)
        e2a0 += g0.x * g0.x + g0.y * g0.y + g0.z * g0.z + g0.w * g0.w;
        e2a1 += g1.x * g1.x + g1.y * g1.y + g1.z * g1.z + g1.w * g1.w;
        ushort4 h0, h1;
        h0.x = f2bf(g0.x); h0.y = f2bf(g0.y); h0.z = f2bf(g0.z); h0.w = f2bf(g0.w);
        h1.x = f2bf(g1.x); h1.y = f2bf(g1.y); h1.z = f2bf(g1.z); h1.w = f2bf(g1.w);
        *(ushort4*)&Asm[buf][row0 * 36 + j0 * 4] = h0;
        *(ushort4*)&Asm[buf][row1 * 36 + j0 * 4] = h1;

        // prefetch kc+1 (A + B) - stays in flight across the raw barrier
        float4 n0, n1; s16x8 nb[4];
        if (kc < 15) {
            n0 = emb4[(size_t)row0 * 128 + (kc + 1) * 8 + j0];
            n1 = emb4[(size_t)row1 * 128 + (kc + 1) * 8 + j0];
#pragma unroll
            for (int nt = 0; nt < 4; ++nt)
                nb[nt] = *(const s16x8*)(pBf +
                    (size_t)((((kc + 1) * 4 + quad) * 4 + nt) * 16 + l15) * 8);
        }

        // drain LDS writes only; vmcnt (prefetch) NOT drained
        asm volatile("s_waitcnt lgkmcnt(0)\n\ts_barrier" ::: "memory");

        s16x8 a = *(const s16x8*)&Asm[buf][(wv * 16 + l15) * 36 + quad * 8];
#pragma unroll
        for (int nt = 0; nt < 4; ++nt)
            acc[nt] = __builtin_amdgcn_mfma_f32_16x16x32_bf16(a, bf[nt], acc[nt], 0, 0, 0);

        g0 = n0; g1 = n1;
#pragma unroll
        for (int nt = 0; nt < 4; ++nt) bf[nt] = nb[nt];
    }

    // flush e2 (8 consecutive lanes share a row)
    float v0 = e2a0;
    v0 += __shfl_xor(v0, 1, 64); v0 += __shfl_xor(v0, 2, 64); v0 += __shfl_xor(v0, 4, 64);
    float v1 = e2a1;
    v1 += __shfl_xor(v1, 1, 64); v1 += __shfl_xor(v1, 2, 64); v1 += __shfl_xor(v1, 4, 64);
    if ((lane & 7) == 0) {
        e2s[wv * 8 + (lane >> 3)]      = v0;
        e2s[32 + wv * 8 + (lane >> 3)] = v1;
    }
    __syncthreads();

    // epilogue: C/D layout col = nt*16 + l15, row = quad*4 + reg
    float nlls = 0.f, corr = 0.f;
#pragma unroll
    for (int reg = 0; reg < 4; ++reg) {
        int rloc = wv * 16 + quad * 4 + reg;
        float e2v = e2s[rloc];
        float lg[4];
#pragma unroll
        for (int nt = 0; nt < 4; ++nt) {
            float d2 = e2v + p2[nt * 16 + l15] - 2.f * acc[nt][reg];
            d2 = fmaxf(d2, 1e-12f);
            lg[nt] = -sqrtf(d2);
        }
        float mv = lg[0]; int mc = l15;
#pragma unroll
        for (int nt = 1; nt < 4; ++nt) {
            int cix = nt * 16 + l15;
            if (lg[nt] > mv) { mv = lg[nt]; mc = cix; }
        }
#pragma unroll
        for (int o = 1; o < 16; o <<= 1) {
            float mo = __shfl_xor(mv, o, 64);
            int   co = __shfl_xor(mc, o, 64);
            if (mo > mv || (mo == mv && co < mc)) { mv = mo; mc = co; }
        }
        int lab = labels[rbase + rloc];
        float se = 0.f, ll = 0.f;
#pragma unroll
        for (int nt = 0; nt < 4; ++nt) se += __expf(lg[nt] - mv);
        if ((lab & 15) == l15) ll = lg[lab >> 4];
#pragma unroll
        for (int o = 1; o < 16; o <<= 1) {
            se += __shfl_xor(se, o, 64);
            ll += __shfl_xor(ll, o, 64);
        }
        if (l15 == 0) {
            nlls += __logf(se) + mv - ll;
            corr += (mc == lab) ? 1.f : 0.f;
        }
    }
#pragma unroll
    for (int o = 1; o < 64; o <<= 1) {
        nlls += __shfl_xor(nlls, o, 64);
        corr += __shfl_xor(corr, o, 64);
    }
    if (lane == 0) { rb[wv] = nlls; rb[4 + wv] = corr; }
    __syncthreads();
    if (t == 0) {
        atomicAdd(lossAcc, rb[0] + rb[1] + rb[2] + rb[3]);
        atomicAdd(accAcc, rb[4] + rb[5] + rb[6] + rb[7]);
        __threadfence();
        unsigned int tk = atomicAdd(doneCnt, 1u);
        if (tk == LGRID - 1) {   // last block: all atomics visible
            float ls  = atomicAdd(lossAcc, 0.f);   // device-scope read
            float as_ = atomicAdd(accAcc, 0.f);
            out[0] = ls * (1.f / NROWS);
            out[1] = as_ * (1.f / NROWS);
        }
    }
}

extern "C" void kernel_launch(void* const* d_in, const int* in_sizes, int n_in,
                              void* d_out, int out_size, void* d_ws, size_t ws_size,
                              hipStream_t stream) {
    const float* emb    = (const float*)d_in[0];
    const int*   labels = (const int*)d_in[1];
    float* out = (float*)d_out;

    float* wsf = (float*)d_ws;
    int*   wsi = (int*)d_ws;
    float*          protoSum = wsf + WS_PROTOSUM;
    int*            cursors  = wsi + WS_CURSORS;
    float*          lossAcc  = wsf + WS_LOSS;
    float*          accAcc   = wsf + WS_ACC;
    unsigned int*   doneCnt  = (unsigned int*)(wsi + WS_DONE);
    float*          p2       = wsf + WS_P2;
    int*            perm     = wsi + WS_PERM;
    unsigned short* pBf      = (unsigned short*)(wsf + WS_PBF);

    hipMemsetAsync(d_ws, 0, MEMSET_WORDS * sizeof(int), stream);

    k_scatter<<<NROWS / 256, 256, 0, stream>>>(labels, cursors, perm);
    k_psum<<<NCLS * 32, 256, 0, stream>>>(emb, cursors, perm, protoSum);
    k_protofin<<<NCLS, 512, 0, stream>>>(protoSum, cursors, pBf, p2);
    k_logits<<<LGRID, 256, 0, stream>>>(emb, labels, pBf, p2,
                                        lossAcc, accAcc, doneCnt, out);
}